// Round 4
// baseline (100.553 us; speedup 1.0000x reference)
//
#include <hip/hip_runtime.h>
#include <hip/hip_bf16.h>
#include <math.h>

#define HH 4
#define BB 4
#define CC 32
#define VV 1000
#define LL 12
#define EE 20000
#define NBL (BB * LL)   /* 48 */
#define SS (HH * NBL)   /* 192 */
#define RCAP 128        /* padded CSR row capacity (max deg ~45 for this input) */
#define LALPHA 0.2f
#define NEG_CAP_F -9000000000000000.0f

typedef unsigned int uint;
typedef unsigned short ushort;

static __device__ __forceinline__ ushort f2bf(float f) {
  __hip_bfloat16 h = __float2bfloat16(f);
  return *(ushort*)&h;
}

// ---------------------------------------------------------------------------
// k_h: h_g[slab][v][c] (bf16), slab=h*NBL+b*LL+l; h = x·W.
// s_src/s_dst[slab][v] via factored wa = W·a (no cross-lane shuffles).
// ---------------------------------------------------------------------------
__global__ __launch_bounds__(256) void k_h(const float* __restrict__ x,
                                           const float* __restrict__ W,
                                           const float* __restrict__ a,
                                           __hip_bfloat16* __restrict__ h_g,
                                           float* __restrict__ s_src,
                                           float* __restrict__ s_dst) {
  __shared__ float W_lds[HH * CC * CC];   // 16 KB
  __shared__ float a_lds[HH * 2 * CC];    // 1 KB
  __shared__ float x_lds[CC * 8 * LL];    // 12 KB
  __shared__ float wa[HH][2][CC];         // 1 KB
  const int tid = threadIdx.x;
  const int b = blockIdx.y;
  const int v0 = blockIdx.x * 8;

  for (int i = tid; i < HH * CC * CC; i += 256) W_lds[i] = W[i];
  a_lds[tid] = a[tid];   // HH*2*CC == 256
  for (int i = tid; i < CC * 8 * LL; i += 256) {
    int ci = i / (8 * LL);
    int r = i - ci * (8 * LL);
    x_lds[i] = x[(b * CC + ci) * (VV * LL) + v0 * LL + r];
  }
  __syncthreads();

  // wa[h][which][ci] = sum_c W[h][ci][c] * a[h][which][c]
  {
    int h = tid >> 6, rest = tid & 63, which = rest >> 5, ci = rest & 31;
    float acc = 0.f;
#pragma unroll
    for (int c = 0; c < CC; ++c)
      acc = fmaf(W_lds[h * CC * CC + ci * CC + c],
                 a_lds[h * 2 * CC + which * CC + c], acc);
    wa[h][which][ci] = acc;
  }
  __syncthreads();

  const int vp = tid >> 5;   // which v in chunk of 8
  const int c = tid & 31;    // output channel

  float acc[HH][LL];
#pragma unroll
  for (int h = 0; h < HH; ++h)
#pragma unroll
    for (int l = 0; l < LL; ++l) acc[h][l] = 0.f;

#pragma unroll 4
  for (int ci = 0; ci < CC; ++ci) {
    float xv[LL];
#pragma unroll
    for (int l = 0; l < LL; ++l) xv[l] = x_lds[ci * 96 + vp * LL + l];
#pragma unroll
    for (int h = 0; h < HH; ++h) {
      float w = W_lds[h * CC * CC + ci * CC + c];
#pragma unroll
      for (int l = 0; l < LL; ++l) acc[h][l] = fmaf(xv[l], w, acc[h][l]);
    }
  }

  const int v = v0 + vp;
#pragma unroll
  for (int h = 0; h < HH; ++h)
#pragma unroll
    for (int l = 0; l < LL; ++l) {
      int slab = h * NBL + b * LL + l;
      h_g[((size_t)slab * VV + v) * CC + c] = __float2bfloat16(acc[h][l]);
    }

  // s_src/s_dst: thread (vp2,q) covers combos cb=q and cb=q+32 (q<16)
  {
    int q = tid & 31;
    int vp2 = tid >> 5;
    for (int cb = q; cb < HH * LL; cb += 32) {
      int h = cb / LL, l = cb - (cb / LL) * LL;
      float as = 0.f, ad = 0.f;
#pragma unroll
      for (int ci = 0; ci < CC; ++ci) {
        float xr = x_lds[ci * 96 + vp2 * LL + l];
        as = fmaf(xr, wa[h][0][ci], as);
        ad = fmaf(xr, wa[h][1][ci], ad);
      }
      int slab = h * NBL + b * LL + l;
      s_src[slab * VV + v0 + vp2] = as;
      s_dst[slab * VV + v0 + vp2] = ad;
    }
  }
}

// ---------------------------------------------------------------------------
// k_scatter: padded-CSR build via atomic append (cnt pre-zeroed by memset).
// ---------------------------------------------------------------------------
__global__ __launch_bounds__(256) void k_scatter(const int* __restrict__ ei,
                                                 const float* __restrict__ ev,
                                                 int* __restrict__ cnt,
                                                 int* __restrict__ csr_dst,
                                                 float* __restrict__ csr_lv) {
  int e = blockIdx.x * 256 + threadIdx.x;
  if (e >= EE) return;
  int r = ei[e];
  int d = ei[EE + e];
  int pos = atomicAdd(&cnt[r], 1);
  if (pos < RCAP) {
    csr_dst[r * RCAP + pos] = d;
    csr_lv[r * RCAP + pos] = fmaxf(__logf(ev[e]), NEG_CAP_F);
  }
}

// ---------------------------------------------------------------------------
// k_agg: block = 8 waves = (2 v) x (4 h); wave handles one (v, bl, h).
// Phase 1: 64 lanes compute ee for <=64 edges in parallel (registers).
// Phase 2: 8 edges/iter via shfl broadcast with a WAVE-UNIFORM trip count
//          (all 64 lanes active for every ds_bpermute — divergent-exit
//          broadcast was round-3's bug). Out-of-range edges have eer=0,
//          dstr=0, so they contribute exactly zero.
// Lane gathers 4 channels (uint2 of bf16) from h_g. Writes hp = num/rs as
// bf16 to tmp[bl][v][h][c]. XCD-swizzled per bl-stretch.
// ---------------------------------------------------------------------------
__global__ __launch_bounds__(512) void k_agg(const uint* __restrict__ hgp,
                                             const float* __restrict__ s_src,
                                             const float* __restrict__ s_dst,
                                             const int* __restrict__ cnt,
                                             const int* __restrict__ csr_dst,
                                             const float* __restrict__ csr_lv,
                                             uint* __restrict__ tmp) {
  const int i = blockIdx.x;
  const int xcd = i & 7;
  const int q = i >> 3;                    // 0..2999
  const int bl = xcd + 8 * (q / 500);      // 0..47
  const int vp = (q % 500) * 2;
  const int w = threadIdx.x >> 6;
  const int h = w & 3;
  const int v = vp + (w >> 2);
  const int lane = threadIdx.x & 63;
  const int jj = lane >> 3;                // 8 edge groups
  const int c3 = lane & 7;                 // uint2 index (4 channels)

  const int slab = h * NBL + bl;
  const float ssv = s_src[slab * VV + v];
  const float* sdb = s_dst + slab * VV;
  const uint2* hgb = (const uint2*)hgp + (size_t)slab * (VV * CC / 4);
  int deg = cnt[v];
  if (deg > RCAP) deg = RCAP;
  const int rbase = v * RCAP;

  float num0 = 0.f, num1 = 0.f, num2 = 0.f, num3 = 0.f, rs = 0.f;

  for (int base = 0; base < deg; base += 64) {
    // phase 1: per-lane ee (lanes beyond deg hold eer=0, dstr=0)
    int idx = base + lane;
    float eer = 0.f;
    int dstr = 0;
    if (idx < deg) {
      dstr = csr_dst[rbase + idx];
      float lv = csr_lv[rbase + idx];
      float s = ssv + sdb[dstr];
      float lr = s > 0.f ? s : LALPHA * s;
      eer = __expf(-lr) * lv;
    }
    int m = deg - base;
    if (m > 64) m = 64;
    // phase 2: uniform trip count — every lane executes every shfl
    int iters = (m + 7) >> 3;
    for (int t = 0; t < iters; ++t) {
      int k = (t << 3) + jj;               // <= 63 always
      int d = __shfl(dstr, k);
      float e = __shfl(eer, k);
      uint2 g = hgb[d * 8 + c3];
      num0 = fmaf(e, __uint_as_float(g.x << 16), num0);
      num1 = fmaf(e, __uint_as_float(g.x & 0xffff0000u), num1);
      num2 = fmaf(e, __uint_as_float(g.y << 16), num2);
      num3 = fmaf(e, __uint_as_float(g.y & 0xffff0000u), num3);
      rs += e;
    }
  }

  // reduce across the 8 jj-groups (xor 8,16,32)
#pragma unroll
  for (int m = 8; m <= 32; m <<= 1) {
    num0 += __shfl_xor(num0, m);
    num1 += __shfl_xor(num1, m);
    num2 += __shfl_xor(num2, m);
    num3 += __shfl_xor(num3, m);
    rs += __shfl_xor(rs, m);
  }

  if (jj == 0) {
    float inv = 1.f / rs;
    uint p0 = (uint)f2bf(num0 * inv) | ((uint)f2bf(num1 * inv) << 16);
    uint p1 = (uint)f2bf(num2 * inv) | ((uint)f2bf(num3 * inv) << 16);
    uint2* op = (uint2*)tmp + ((bl * VV + v) * HH + h) * 8 + c3;
    *op = make_uint2(p0, p1);
  }
}

// ---------------------------------------------------------------------------
// k_fin: out[b][c][v][l] = elu(0.25 * sum_h tmp[bl][v][h][c]); LDS transpose.
// ---------------------------------------------------------------------------
__global__ __launch_bounds__(256) void k_fin(const uint* __restrict__ tmp,
                                             float* __restrict__ outp) {
  __shared__ float t[CC][97];
  const int b = blockIdx.y;
  const int v0 = blockIdx.x * 8;
  const int tid = threadIdx.x;
  const int c2 = tid & 15, vi = (tid >> 4) & 7, half = tid >> 7;
#pragma unroll
  for (int li = 0; li < 6; ++li) {
    int l = half * 6 + li;
    int bl = b * LL + l;
    int base = ((bl * VV + v0 + vi) * HH) * 16 + c2;
    float a0 = 0.f, a1 = 0.f;
#pragma unroll
    for (int h = 0; h < HH; ++h) {
      uint g = tmp[base + h * 16];
      a0 += __uint_as_float(g << 16);
      a1 += __uint_as_float(g & 0xffff0000u);
    }
    a0 *= 0.25f;
    a1 *= 0.25f;
    a0 = a0 > 0.f ? a0 : expm1f(a0);
    a1 = a1 > 0.f ? a1 : expm1f(a1);
    t[2 * c2][vi * LL + l] = a0;
    t[2 * c2 + 1][vi * LL + l] = a1;
  }
  __syncthreads();
  {
    int c = tid >> 3, k = tid & 7;
    const float* src = &t[c][k * LL];
    float* op = &outp[((size_t)(b * CC + c) * VV + v0 + k) * LL];
#pragma unroll
    for (int j = 0; j < 3; ++j) {
      float4 w = {src[4 * j], src[4 * j + 1], src[4 * j + 2], src[4 * j + 3]};
      *(float4*)(op + 4 * j) = w;
    }
  }
}

// ---------------------------------------------------------------------------
extern "C" void kernel_launch(void* const* d_in, const int* in_sizes, int n_in,
                              void* d_out, int out_size, void* d_ws, size_t ws_size,
                              hipStream_t stream) {
  const float* x = (const float*)d_in[0];
  const float* W = (const float*)d_in[1];
  const float* a = (const float*)d_in[2];
  const int* ei = (const int*)d_in[3];
  const float* ev = (const float*)d_in[4];
  float* out = (float*)d_out;
  float* ws = (float*)d_ws;

  size_t o = 0;
  uint* h_g = (uint*)(ws + o);      o += (size_t)SS * VV * CC / 2;   // bf16, 12.3 MB
  float* s_src = ws + o;            o += SS * VV;
  float* s_dst = ws + o;            o += SS * VV;
  uint* tmp = (uint*)(ws + o);      o += (size_t)NBL * VV * HH * CC / 2;  // bf16
  int* cnt = (int*)(ws + o);        o += 1024;
  int* csr_dst = (int*)(ws + o);    o += VV * RCAP;
  float* csr_lv = ws + o;           o += VV * RCAP;

  hipMemsetAsync(cnt, 0, VV * sizeof(int), stream);

  dim3 gA(VV / 8, BB);
  k_h<<<gA, 256, 0, stream>>>(x, W, a, (__hip_bfloat16*)h_g, s_src, s_dst);

  k_scatter<<<(EE + 255) / 256, 256, 0, stream>>>(ei, ev, cnt, csr_dst, csr_lv);

  const int nblk = NBL * (VV / 2);  // 24000 blocks, 512 threads
  k_agg<<<nblk, 512, 0, stream>>>(h_g, s_src, s_dst, cnt, csr_dst, csr_lv, tmp);

  k_fin<<<dim3(VV / 8, BB), 256, 0, stream>>>(tmp, out);
}

// Round 5
// 69.527 us; speedup vs baseline: 1.4463x; 1.4463x over previous
//
#include <hip/hip_runtime.h>
#include <hip/hip_bf16.h>
#include <math.h>

#define HH 4
#define BB 4
#define CC 32
#define VV 1000
#define LL 12
#define EE 20000
#define NBL (BB * LL)   /* 48 */
#define SS (HH * NBL)   /* 192 */
#define RCAP 128        /* padded CSR row capacity (max deg ~45 for this input) */
#define LALPHA 0.2f
#define NEG_CAP_F -9000000000000000.0f

typedef unsigned int uint;
typedef unsigned short ushort;

// ---------------------------------------------------------------------------
// k_h: h_g[slab][v][c] (bf16), slab=h*NBL+b*LL+l; h = x·W.
// s_src/s_dst[slab][v] via factored wa = W·a. Also zeroes cnt[] (first 4
// blocks) so no separate memset dispatch is needed.
// ---------------------------------------------------------------------------
__global__ __launch_bounds__(256) void k_h(const float* __restrict__ x,
                                           const float* __restrict__ W,
                                           const float* __restrict__ a,
                                           ushort* __restrict__ h_g,
                                           float* __restrict__ s_src,
                                           float* __restrict__ s_dst,
                                           int* __restrict__ cnt) {
  if (blockIdx.y == 0 && blockIdx.x < 4) {
    cnt[blockIdx.x * 256 + threadIdx.x] = 0;
  }

  __shared__ float W_lds[HH * CC * CC];   // 16 KB
  __shared__ float a_lds[HH * 2 * CC];    // 1 KB
  __shared__ float x_lds[CC * 8 * LL];    // 12 KB
  __shared__ float wa[HH][2][CC];         // 1 KB
  const int tid = threadIdx.x;
  const int b = blockIdx.y;
  const int v0 = blockIdx.x * 8;

  for (int i = tid; i < HH * CC * CC; i += 256) W_lds[i] = W[i];
  a_lds[tid] = a[tid];   // HH*2*CC == 256
  for (int i = tid; i < CC * 8 * LL; i += 256) {
    int ci = i / (8 * LL);
    int r = i - ci * (8 * LL);
    x_lds[i] = x[(b * CC + ci) * (VV * LL) + v0 * LL + r];
  }
  __syncthreads();

  // wa[h][which][ci] = sum_c W[h][ci][c] * a[h][which][c]
  {
    int h = tid >> 6, rest = tid & 63, which = rest >> 5, ci = rest & 31;
    float acc = 0.f;
#pragma unroll
    for (int c = 0; c < CC; ++c)
      acc = fmaf(W_lds[h * CC * CC + ci * CC + c],
                 a_lds[h * 2 * CC + which * CC + c], acc);
    wa[h][which][ci] = acc;
  }
  __syncthreads();

  const int vp = tid >> 5;   // which v in chunk of 8
  const int c = tid & 31;    // output channel

  float acc[HH][LL];
#pragma unroll
  for (int h = 0; h < HH; ++h)
#pragma unroll
    for (int l = 0; l < LL; ++l) acc[h][l] = 0.f;

#pragma unroll 4
  for (int ci = 0; ci < CC; ++ci) {
    float xv[LL];
#pragma unroll
    for (int l = 0; l < LL; ++l) xv[l] = x_lds[ci * 96 + vp * LL + l];
#pragma unroll
    for (int h = 0; h < HH; ++h) {
      float w = W_lds[h * CC * CC + ci * CC + c];
#pragma unroll
      for (int l = 0; l < LL; ++l) acc[h][l] = fmaf(xv[l], w, acc[h][l]);
    }
  }

  const int v = v0 + vp;
#pragma unroll
  for (int h = 0; h < HH; ++h)
#pragma unroll
    for (int l = 0; l < LL; ++l) {
      int slab = h * NBL + b * LL + l;
      __hip_bfloat16 bf = __float2bfloat16(acc[h][l]);
      h_g[((size_t)slab * VV + v) * CC + c] = *(ushort*)&bf;
    }

  // s_src/s_dst: thread (vp2,q) covers combos cb=q and cb=q+32 (q<16)
  {
    int q = tid & 31;
    int vp2 = tid >> 5;
    for (int cb = q; cb < HH * LL; cb += 32) {
      int h = cb / LL, l = cb - (cb / LL) * LL;
      float as = 0.f, ad = 0.f;
#pragma unroll
      for (int ci = 0; ci < CC; ++ci) {
        float xr = x_lds[ci * 96 + vp2 * LL + l];
        as = fmaf(xr, wa[h][0][ci], as);
        ad = fmaf(xr, wa[h][1][ci], ad);
      }
      int slab = h * NBL + b * LL + l;
      s_src[slab * VV + v0 + vp2] = as;
      s_dst[slab * VV + v0 + vp2] = ad;
    }
  }
}

// ---------------------------------------------------------------------------
// k_scatter: padded-CSR build via atomic append; entry = {dst, lv} packed.
// ---------------------------------------------------------------------------
__global__ __launch_bounds__(256) void k_scatter(const int* __restrict__ ei,
                                                 const float* __restrict__ ev,
                                                 int* __restrict__ cnt,
                                                 uint2* __restrict__ csr) {
  int e = blockIdx.x * 256 + threadIdx.x;
  if (e >= EE) return;
  int r = ei[e];
  int d = ei[EE + e];
  int pos = atomicAdd(&cnt[r], 1);
  if (pos < RCAP) {
    float lv = fmaxf(__logf(ev[e]), NEG_CAP_F);
    csr[r * RCAP + pos] = make_uint2((uint)d, __float_as_uint(lv));
  }
}

// ---------------------------------------------------------------------------
// k_agg: one wave per (v, bl); h-loop inside; no shuffles in hot loop.
// Phase A (16-edge chunk): lanes = 16 edges x 4 h -> one exp per (edge,h),
//   {dst, ee} packed into per-warp LDS (intra-wave, no barrier; double-
//   buffered by chunk parity).
// Phase B: lanes = 2 edges x 32 channels; ds_read_b64 broadcast + bf16
//   ushort gather + fma. Tail: single xor-32 reduce per h, then fused
//   mean-over-h + ELU + direct write to out[b][c][v][l].
// XCD swizzle: 250 consecutive blocks (same bl, consecutive v) per XCD slot.
// ---------------------------------------------------------------------------
__global__ __launch_bounds__(256) void k_agg(const ushort* __restrict__ hg,
                                             const float* __restrict__ s_src,
                                             const float* __restrict__ s_dst,
                                             const int* __restrict__ cnt,
                                             const uint2* __restrict__ csr,
                                             float* __restrict__ outp) {
  __shared__ uint2 ed[4][2][HH][16];   // [warp][parity][h][idx] = {dst, ee}
  const int i = blockIdx.x;
  const int xcd = i & 7;
  const int q = i >> 3;                // 0..1499
  const int bl = xcd * 6 + q / 250;    // 0..47
  const int vb = q % 250;
  const int warp = threadIdx.x >> 6;
  const int v = vb * 4 + warp;
  const int lane = threadIdx.x & 63;
  const int b = bl / LL, l = bl - b * LL;

  int deg = cnt[v];
  if (deg > RCAP) deg = RCAP;
  const int rbase = v * RCAP;

  // phase-A role: lane = ha*16 + ia
  const int ha = lane >> 4;
  const int ia = lane & 15;
  const int slabA = ha * NBL + bl;
  const float ssv = s_src[slabA * VV + v];
  const float* sdbA = s_dst + slabA * VV;

  // phase-B role: lane = jj*32 + c
  const int jj = lane >> 5;
  const int c = lane & 31;

  float num[HH] = {0.f, 0.f, 0.f, 0.f};
  float rs[HH] = {0.f, 0.f, 0.f, 0.f};
  const ushort* hgs[HH];
#pragma unroll
  for (int h = 0; h < HH; ++h)
    hgs[h] = hg + (size_t)(h * NBL + bl) * (VV * CC);

  for (int base = 0; base < deg; base += 16) {
    const int par = (base >> 4) & 1;
    // ---- phase A: one (edge,h) per lane ----
    int e = base + ia;
    float eev = 0.f;
    int d = 0;
    if (e < deg) {
      uint2 ent = csr[rbase + e];
      d = (int)ent.x;
      float lv = __uint_as_float(ent.y);
      float s = ssv + sdbA[d];
      float lr = s > 0.f ? s : LALPHA * s;
      eev = __expf(-lr) * lv;
    }
    ed[warp][par][ha][ia] = make_uint2((uint)d, __float_as_uint(eev));

    // ---- phase B: 2 edges x 32 channels per iter ----
    int m = deg - base;
    if (m > 16) m = 16;
    int iters = (m + 1) >> 1;
    for (int t = 0; t < iters; ++t) {
      int idx = t * 2 + jj;   // <= 15 always (slots >= m hold ee=0, dst=0)
#pragma unroll
      for (int h = 0; h < HH; ++h) {
        uint2 p = ed[warp][par][h][idx];
        float e2 = __uint_as_float(p.y);
        ushort gv = hgs[h][p.x * CC + c];
        num[h] = fmaf(e2, __uint_as_float((uint)gv << 16), num[h]);
        rs[h] += e2;
      }
    }
  }

  // tail: reduce jj halves, combine heads, ELU, write out
  float acc = 0.f;
#pragma unroll
  for (int h = 0; h < HH; ++h) {
    float n = num[h] + __shfl_xor(num[h], 32);
    float r = rs[h] + __shfl_xor(rs[h], 32);
    acc += __fdividef(n, r);
  }
  if (jj == 0) {
    float mv = acc * 0.25f;
    float res = mv > 0.f ? mv : expm1f(mv);
    outp[((size_t)(b * CC + c) * VV + v) * LL + l] = res;
  }
}

// ---------------------------------------------------------------------------
extern "C" void kernel_launch(void* const* d_in, const int* in_sizes, int n_in,
                              void* d_out, int out_size, void* d_ws, size_t ws_size,
                              hipStream_t stream) {
  const float* x = (const float*)d_in[0];
  const float* W = (const float*)d_in[1];
  const float* a = (const float*)d_in[2];
  const int* ei = (const int*)d_in[3];
  const float* ev = (const float*)d_in[4];
  float* out = (float*)d_out;
  float* ws = (float*)d_ws;

  size_t o = 0;
  ushort* h_g = (ushort*)(ws + o);  o += (size_t)SS * VV * CC / 2;   // bf16, 12.3 MB
  float* s_src = ws + o;            o += SS * VV;
  float* s_dst = ws + o;            o += SS * VV;
  int* cnt = (int*)(ws + o);        o += 1024;
  uint2* csr = (uint2*)(ws + o);    o += (size_t)VV * RCAP * 2;      // {dst, lv}

  dim3 gA(VV / 8, BB);
  k_h<<<gA, 256, 0, stream>>>(x, W, a, h_g, s_src, s_dst, cnt);

  k_scatter<<<(EE + 255) / 256, 256, 0, stream>>>(ei, ev, cnt, csr);

  const int nblk = NBL * (VV / 4);  // 12000 blocks, 4 waves each
  k_agg<<<nblk, 256, 0, stream>>>(h_g, s_src, s_dst, cnt, csr, out);
}

// Round 6
// 65.859 us; speedup vs baseline: 1.5268x; 1.0557x over previous
//
#include <hip/hip_runtime.h>
#include <hip/hip_bf16.h>
#include <math.h>

#define HH 4
#define BB 4
#define CC 32
#define VV 1000
#define LL 12
#define EE 20000
#define NBL (BB * LL)   /* 48 */
#define SS (HH * NBL)   /* 192 */
#define RCAP 128        /* padded CSR row capacity (max deg ~45 for this input) */
#define LALPHA 0.2f
#define NEG_CAP_F -9000000000000000.0f

typedef unsigned int uint;
typedef unsigned short ushort;

// ---------------------------------------------------------------------------
// k_h: h_g[slab][v][c] (bf16), slab=h*NBL+b*LL+l; h = x·W.
// Grid (125, BB, 2): z picks an h-pair -> 1000 blocks (~4 waves/SIMD).
// s_src/s_dst[slab][v] via factored wa = W·a (rotation-indexed, conflict-free).
// Block (z==0,y==0,x<4) zeroes cnt[].
// ---------------------------------------------------------------------------
__global__ __launch_bounds__(256) void k_h(const float* __restrict__ x,
                                           const float* __restrict__ W,
                                           const float* __restrict__ a,
                                           ushort* __restrict__ h_g,
                                           float* __restrict__ s_src,
                                           float* __restrict__ s_dst,
                                           int* __restrict__ cnt) {
  const int hp = blockIdx.z;        // h-pair: h = hp*2 + hh
  if (hp == 0 && blockIdx.y == 0 && blockIdx.x < 4) {
    cnt[blockIdx.x * 256 + threadIdx.x] = 0;
  }

  __shared__ float W_lds[2 * CC * CC];    // 8 KB (this h-pair)
  __shared__ float a_lds[2 * 2 * CC];     // 512 B
  __shared__ float x_lds[CC * 8 * LL];    // 12 KB
  __shared__ float wa[2][2][CC];          // 512 B
  const int tid = threadIdx.x;
  const int b = blockIdx.y;
  const int v0 = blockIdx.x * 8;

  for (int i = tid; i < 2 * CC * CC; i += 256) W_lds[i] = W[hp * 2 * CC * CC + i];
  if (tid < 128) a_lds[tid] = a[hp * 128 + tid];
  for (int i = tid; i < CC * 8 * LL; i += 256) {
    int ci = i / (8 * LL);
    int r = i - ci * (8 * LL);
    x_lds[i] = x[(b * CC + ci) * (VV * LL) + v0 * LL + r];
  }
  __syncthreads();

  // wa[hh][which][ci] = sum_c W[hh][ci][c]*a[hh][which][c], rotated index
  if (tid < 128) {
    int hh = tid >> 6, rest = tid & 63, which = rest >> 5, ci = rest & 31;
    float acc = 0.f;
#pragma unroll
    for (int k = 0; k < CC; ++k) {
      int c = (k + ci) & 31;
      acc = fmaf(W_lds[hh * CC * CC + ci * CC + c],
                 a_lds[hh * 2 * CC + which * CC + c], acc);
    }
    wa[hh][which][ci] = acc;
  }
  __syncthreads();

  const int vp = tid >> 5;   // which v in chunk of 8
  const int c = tid & 31;    // output channel

  float acc[2][LL];
#pragma unroll
  for (int hh = 0; hh < 2; ++hh)
#pragma unroll
    for (int l = 0; l < LL; ++l) acc[hh][l] = 0.f;

#pragma unroll 4
  for (int ci = 0; ci < CC; ++ci) {
    float xv[LL];
#pragma unroll
    for (int l = 0; l < LL; ++l) xv[l] = x_lds[ci * 96 + vp * LL + l];
#pragma unroll
    for (int hh = 0; hh < 2; ++hh) {
      float w = W_lds[hh * CC * CC + ci * CC + c];
#pragma unroll
      for (int l = 0; l < LL; ++l) acc[hh][l] = fmaf(xv[l], w, acc[hh][l]);
    }
  }

  const int v = v0 + vp;
#pragma unroll
  for (int hh = 0; hh < 2; ++hh)
#pragma unroll
    for (int l = 0; l < LL; ++l) {
      int slab = (hp * 2 + hh) * NBL + b * LL + l;
      __hip_bfloat16 bf = __float2bfloat16(acc[hh][l]);
      h_g[((size_t)slab * VV + v) * CC + c] = *(ushort*)&bf;
    }

  // s_src/s_dst: 24 (hh,l) combos over lanes q<24 of each vp2 group
  {
    int q = tid & 31;
    int vp2 = tid >> 5;
    if (q < 24) {
      int hh = q / LL, l = q - (q / LL) * LL;
      float as = 0.f, ad = 0.f;
#pragma unroll
      for (int ci = 0; ci < CC; ++ci) {
        float xr = x_lds[ci * 96 + vp2 * LL + l];
        as = fmaf(xr, wa[hh][0][ci], as);
        ad = fmaf(xr, wa[hh][1][ci], ad);
      }
      int slab = (hp * 2 + hh) * NBL + b * LL + l;
      s_src[slab * VV + v0 + vp2] = as;
      s_dst[slab * VV + v0 + vp2] = ad;
    }
  }
}

// ---------------------------------------------------------------------------
// k_scatter: padded-CSR build via atomic append; entry = {dst, lv} packed.
// ---------------------------------------------------------------------------
__global__ __launch_bounds__(256) void k_scatter(const int* __restrict__ ei,
                                                 const float* __restrict__ ev,
                                                 int* __restrict__ cnt,
                                                 uint2* __restrict__ csr) {
  int e = blockIdx.x * 256 + threadIdx.x;
  if (e >= EE) return;
  int r = ei[e];
  int d = ei[EE + e];
  int pos = atomicAdd(&cnt[r], 1);
  if (pos < RCAP) {
    float lv = fmaxf(__logf(ev[e]), NEG_CAP_F);
    csr[r * RCAP + pos] = make_uint2((uint)d, __float_as_uint(lv));
  }
}

// ---------------------------------------------------------------------------
// k_agg: one wave per (v, bl); h-loop inside; no shuffles in hot loop.
// Phase A (16-edge chunk): lanes = 16 edges x 4 h -> one exp per (edge,h);
//   dst (u32) + ee (h-minor float4) in per-warp LDS, double-buffered by
//   chunk parity. Same-wave DS ordering -> no barrier.
// Phase B: lanes = 4 edge-slots (ii) x 16 channel-pairs (cq); per iter:
//   b32 dst broadcast + b128 ee (all 4 h) + 4 uint bf16-pair gathers +
//   8 fma. Tail: xor-16/32 reduce, fused mean-over-h + ELU, direct write.
// XCD swizzle: 250 consecutive blocks (same bl, consecutive v) per XCD slot.
// ---------------------------------------------------------------------------
__global__ __launch_bounds__(256) void k_agg(const ushort* __restrict__ hg,
                                             const float* __restrict__ s_src,
                                             const float* __restrict__ s_dst,
                                             const int* __restrict__ cnt,
                                             const uint2* __restrict__ csr,
                                             float* __restrict__ outp) {
  __shared__ uint ed_dst[4][2][16];        // [warp][parity][edge]
  __shared__ float ed_ee[4][2][16][HH];    // [warp][parity][edge][h]
  const int i = blockIdx.x;
  const int xcd = i & 7;
  const int q = i >> 3;                // 0..1499
  const int bl = xcd * 6 + q / 250;    // 0..47
  const int vb = q % 250;
  const int warp = threadIdx.x >> 6;
  const int v = vb * 4 + warp;
  const int lane = threadIdx.x & 63;
  const int b = bl / LL, l = bl - b * LL;

  int deg = cnt[v];
  if (deg > RCAP) deg = RCAP;
  const int rbase = v * RCAP;

  // phase-A role: lane = ha*16 + ia
  const int ha = lane >> 4;
  const int ia = lane & 15;
  const int slabA = ha * NBL + bl;
  const float ssv = s_src[slabA * VV + v];
  const float* sdbA = s_dst + slabA * VV;

  // phase-B role: lane = ii*16 + cq  (channels 2cq, 2cq+1)
  const int ii = lane >> 4;
  const int cq = lane & 15;

  float num[HH][2];
  float rs[HH];
#pragma unroll
  for (int h = 0; h < HH; ++h) {
    num[h][0] = 0.f; num[h][1] = 0.f; rs[h] = 0.f;
  }
  const uint* hgs[HH];
#pragma unroll
  for (int h = 0; h < HH; ++h)
    hgs[h] = (const uint*)(hg + (size_t)(h * NBL + bl) * (VV * CC));

  for (int base = 0; base < deg; base += 16) {
    const int par = (base >> 4) & 1;
    // ---- phase A: one (edge,h) per lane ----
    int e = base + ia;
    float eev = 0.f;
    int d = 0;
    if (e < deg) {
      uint2 ent = csr[rbase + e];
      d = (int)ent.x;
      float lv = __uint_as_float(ent.y);
      float s = ssv + sdbA[d];
      float lr = s > 0.f ? s : LALPHA * s;
      eev = __expf(-lr) * lv;
    }
    ed_ee[warp][par][ia][ha] = eev;
    if (ha == 0) ed_dst[warp][par][ia] = (uint)d;

    // ---- phase B: 4 edges x 32 channels per iter ----
    int m = deg - base;
    if (m > 16) m = 16;
    int iters = (m + 3) >> 2;
    for (int t = 0; t < iters; ++t) {
      int idx = t * 4 + ii;   // <= 15 always (slots >= m hold ee=0, dst=0)
      uint d2 = ed_dst[warp][par][idx];
      const float4 e4 = *(const float4*)&ed_ee[warp][par][idx][0];
      const uint cix = d2 * (CC / 2) + cq;
#pragma unroll
      for (int h = 0; h < HH; ++h) {
        float eh = (h == 0) ? e4.x : (h == 1) ? e4.y : (h == 2) ? e4.z : e4.w;
        uint g = hgs[h][cix];
        num[h][0] = fmaf(eh, __uint_as_float(g << 16), num[h][0]);
        num[h][1] = fmaf(eh, __uint_as_float(g & 0xffff0000u), num[h][1]);
        rs[h] += eh;
      }
    }
  }

  // tail: reduce across the 4 ii-groups (xor 16, 32)
#pragma unroll
  for (int m = 16; m <= 32; m <<= 1) {
#pragma unroll
    for (int h = 0; h < HH; ++h) {
      num[h][0] += __shfl_xor(num[h][0], m);
      num[h][1] += __shfl_xor(num[h][1], m);
      rs[h] += __shfl_xor(rs[h], m);
    }
  }

  if (ii == 0) {
    float a0 = 0.f, a1 = 0.f;
#pragma unroll
    for (int h = 0; h < HH; ++h) {
      float inv = __frcp_rn(rs[h]);
      a0 = fmaf(num[h][0], inv, a0);
      a1 = fmaf(num[h][1], inv, a1);
    }
    a0 *= 0.25f; a1 *= 0.25f;
    a0 = a0 > 0.f ? a0 : expm1f(a0);
    a1 = a1 > 0.f ? a1 : expm1f(a1);
    size_t o0 = ((size_t)(b * CC + 2 * cq) * VV + v) * LL + l;
    outp[o0] = a0;
    outp[o0 + (size_t)VV * LL] = a1;
  }
}

// ---------------------------------------------------------------------------
extern "C" void kernel_launch(void* const* d_in, const int* in_sizes, int n_in,
                              void* d_out, int out_size, void* d_ws, size_t ws_size,
                              hipStream_t stream) {
  const float* x = (const float*)d_in[0];
  const float* W = (const float*)d_in[1];
  const float* a = (const float*)d_in[2];
  const int* ei = (const int*)d_in[3];
  const float* ev = (const float*)d_in[4];
  float* out = (float*)d_out;
  float* ws = (float*)d_ws;

  size_t o = 0;
  ushort* h_g = (ushort*)(ws + o);  o += (size_t)SS * VV * CC / 2;   // bf16, 12.3 MB
  float* s_src = ws + o;            o += SS * VV;
  float* s_dst = ws + o;            o += SS * VV;
  int* cnt = (int*)(ws + o);        o += 1024;
  uint2* csr = (uint2*)(ws + o);    o += (size_t)VV * RCAP * 2;      // {dst, lv}

  dim3 gA(VV / 8, BB, 2);
  k_h<<<gA, 256, 0, stream>>>(x, W, a, h_g, s_src, s_dst, cnt);

  k_scatter<<<(EE + 255) / 256, 256, 0, stream>>>(ei, ev, cnt, csr);

  const int nblk = NBL * (VV / 4);  // 12000 blocks, 4 waves each
  k_agg<<<nblk, 256, 0, stream>>>(h_g, s_src, s_dst, cnt, csr, out);
}

// Round 7
// 61.053 us; speedup vs baseline: 1.6470x; 1.0787x over previous
//
#include <hip/hip_runtime.h>
#include <hip/hip_bf16.h>
#include <math.h>

#define HH 4
#define BB 4
#define CC 32
#define VV 1000
#define LL 12
#define EE 20000
#define NBL (BB * LL)   /* 48 */
#define SS (HH * NBL)   /* 192 */
#define RCAP 128        /* padded CSR row capacity (max deg ~45 for this input) */
#define LALPHA 0.2f
#define NEG_CAP_F -9000000000000000.0f

typedef unsigned int uint;
typedef unsigned short ushort;

// ---------------------------------------------------------------------------
// k_h: h_g[slab][v][c] (bf16), slab=h*NBL+b*LL+l; h = x·W.
// Block = 2 v x 4 h x 32 c (grid 500 x BB = 2000 blocks, ~8 waves/SIMD).
// vp is wave-uniform -> x row read via readfirstlane-uniform base (SMEM path,
// off the LDS pipe). x_s (3 KB LDS) serves only the s_src/s_dst dots.
// Blocks (y==0, x<4) zero cnt[].
// ---------------------------------------------------------------------------
__global__ __launch_bounds__(256) void k_h(const float* __restrict__ x,
                                           const float* __restrict__ W,
                                           const float* __restrict__ a,
                                           ushort* __restrict__ h_g,
                                           float* __restrict__ s_src,
                                           float* __restrict__ s_dst,
                                           int* __restrict__ cnt) {
  if (blockIdx.y == 0 && blockIdx.x < 4) {
    cnt[blockIdx.x * 256 + threadIdx.x] = 0;
  }

  __shared__ float W_lds[HH * CC * CC];   // 16 KB
  __shared__ float a_lds[HH * 2 * CC];    // 1 KB
  __shared__ float x_s[CC * 2 * LL];      // 3 KB (s-part only)
  __shared__ float wa[HH][2][CC];         // 512 B
  const int tid = threadIdx.x;
  const int b = blockIdx.y;
  const int v0 = blockIdx.x * 2;

  {
    const float4* Wf = (const float4*)W;
    float4* Wl = (float4*)W_lds;
    for (int i = tid; i < HH * CC * CC / 4; i += 256) Wl[i] = Wf[i];
  }
  a_lds[tid] = a[tid];   // HH*2*CC == 256
#pragma unroll
  for (int k = 0; k < 3; ++k) {
    int i = k * 256 + tid;
    int ci = i / 24, r = i - ci * 24;
    x_s[i] = x[(b * CC + ci) * (VV * LL) + v0 * LL + r];
  }
  __syncthreads();

  // wa[h][which][ci] = sum_c W[h][ci][c]*a[h][which][c] (rotated, no conflicts)
  {
    int h = tid >> 6, which = (tid >> 5) & 1, ci = tid & 31;
    float acc = 0.f;
#pragma unroll
    for (int k = 0; k < CC; ++k) {
      int c = (k + ci) & 31;
      acc = fmaf(W_lds[h * CC * CC + ci * CC + c],
                 a_lds[h * 2 * CC + which * CC + c], acc);
    }
    wa[h][which][ci] = acc;
  }
  __syncthreads();

  const int vp = tid >> 7;          // wave-uniform (waves 0,1 -> vp0; 2,3 -> vp1)
  const int h = (tid >> 5) & 3;
  const int c = tid & 31;
  const int v = v0 + vp;

  int xoff = (b * CC) * (VV * LL) + v * LL;
  xoff = __builtin_amdgcn_readfirstlane(xoff);
  const float* xr = x + xoff;

  float acc[LL];
#pragma unroll
  for (int l = 0; l < LL; ++l) acc[l] = 0.f;

#pragma unroll 4
  for (int ci = 0; ci < CC; ++ci) {
    float w = W_lds[h * CC * CC + ci * CC + c];
#pragma unroll
    for (int l = 0; l < LL; ++l)
      acc[l] = fmaf(xr[ci * (VV * LL) + l], w, acc[l]);
  }

  const int slab0 = h * NBL + b * LL;
#pragma unroll
  for (int l = 0; l < LL; ++l) {
    __hip_bfloat16 bf = __float2bfloat16(acc[l]);
    h_g[((size_t)(slab0 + l) * VV + v) * CC + c] = *(ushort*)&bf;
  }

  // s_src/s_dst: 192 threads cover (vp2, h2, l, which)
  if (tid < 192) {
    int which = tid & 1;
    int t2 = tid >> 1;            // 0..95
    int l = t2 % 12;
    int h2 = (t2 / 12) & 3;
    int vp2 = t2 / 48;
    float s = 0.f;
#pragma unroll
    for (int ci = 0; ci < CC; ++ci)
      s = fmaf(x_s[ci * 24 + vp2 * 12 + l], wa[h2][which][ci], s);
    int slab = h2 * NBL + b * LL + l;
    float* dp = which ? s_dst : s_src;
    dp[slab * VV + v0 + vp2] = s;
  }
}

// ---------------------------------------------------------------------------
// k_scatter: padded-CSR build via atomic append; entry = {dst, lv} packed.
// ---------------------------------------------------------------------------
__global__ __launch_bounds__(256) void k_scatter(const int* __restrict__ ei,
                                                 const float* __restrict__ ev,
                                                 int* __restrict__ cnt,
                                                 uint2* __restrict__ csr) {
  int e = blockIdx.x * 256 + threadIdx.x;
  if (e >= EE) return;
  int r = ei[e];
  int d = ei[EE + e];
  int pos = atomicAdd(&cnt[r], 1);
  if (pos < RCAP) {
    float lv = fmaxf(__logf(ev[e]), NEG_CAP_F);
    csr[r * RCAP + pos] = make_uint2((uint)d, __float_as_uint(lv));
  }
}

// ---------------------------------------------------------------------------
// k_agg: one wave per (v, bl).
// Phase A (16-edge chunk): lanes = 16 edges x 4 h -> one exp per (edge,h);
//   all 16 slots rewritten every chunk (slots >= m hold ee=0, dst=0), phases
//   are sequential within the wave -> no double buffer, no barrier.
// Phase B: lane = ii(4 edge-slots) x h(4) x cg(4); per iter: 2 broadcast DS
//   reads + ONE uint4 gather (8 channels of lane's h) + 8 fma.
// Tail: xor-16/32 (edge-slots) then xor-4/8 (heads); fused mean+ELU; 16
// lanes write 2 dwords each. XCD swizzle: same-bl stretches per XCD slot.
// ---------------------------------------------------------------------------
__global__ __launch_bounds__(256) void k_agg(const ushort* __restrict__ hg,
                                             const float* __restrict__ s_src,
                                             const float* __restrict__ s_dst,
                                             const int* __restrict__ cnt,
                                             const uint2* __restrict__ csr,
                                             float* __restrict__ outp) {
  __shared__ uint ed_dst[4][16];        // [warp][edge]
  __shared__ float ed_ee[4][16][HH];    // [warp][edge][h]
  const int i = blockIdx.x;
  const int xcd = i & 7;
  const int q = i >> 3;                // 0..1499
  const int bl = xcd * 6 + q / 250;    // 0..47
  const int vb = q % 250;
  const int warp = threadIdx.x >> 6;
  const int v = vb * 4 + warp;
  const int lane = threadIdx.x & 63;
  const int b = bl / LL, l = bl - b * LL;

  int deg = cnt[v];
  if (deg > RCAP) deg = RCAP;
  const int rbase = v * RCAP;

  // phase-A role: lane = ha*16 + ia
  const int ha = lane >> 4;
  const int ia = lane & 15;
  const int slabA = ha * NBL + bl;
  const float ssv = s_src[slabA * VV + v];
  const float* sdbA = s_dst + slabA * VV;

  // phase-B role: lane = ii*16 + h*4 + cg
  const int ii = lane >> 4;
  const int h = (lane >> 2) & 3;
  const int cg = lane & 3;

  const uint4* hgl = (const uint4*)(hg + (size_t)(h * NBL + bl) * (VV * CC));

  float num[8];
#pragma unroll
  for (int j = 0; j < 8; ++j) num[j] = 0.f;
  float rs = 0.f;

  for (int base = 0; base < deg; base += 16) {
    // ---- phase A ----
    int e = base + ia;
    float eev = 0.f;
    int d = 0;
    if (e < deg) {
      uint2 ent = csr[rbase + e];
      d = (int)ent.x;
      float lv = __uint_as_float(ent.y);
      float s = ssv + sdbA[d];
      float lr = s > 0.f ? s : LALPHA * s;
      eev = __expf(-lr) * lv;
    }
    ed_ee[warp][ia][ha] = eev;
    if (ha == 0) ed_dst[warp][ia] = (uint)d;

    // ---- phase B: 4 edges x (4h x 32c) per iter ----
    int m = deg - base;
    if (m > 16) m = 16;
    int iters = (m + 3) >> 2;
    for (int t = 0; t < iters; ++t) {
      int idx = (t << 2) + ii;     // <= 15 always
      uint d2 = ed_dst[warp][idx];
      float eh = ed_ee[warp][idx][h];
      uint4 g = hgl[d2 * 4 + cg];  // 8 bf16 channels of lane's h
      num[0] = fmaf(eh, __uint_as_float(g.x << 16), num[0]);
      num[1] = fmaf(eh, __uint_as_float(g.x & 0xffff0000u), num[1]);
      num[2] = fmaf(eh, __uint_as_float(g.y << 16), num[2]);
      num[3] = fmaf(eh, __uint_as_float(g.y & 0xffff0000u), num[3]);
      num[4] = fmaf(eh, __uint_as_float(g.z << 16), num[4]);
      num[5] = fmaf(eh, __uint_as_float(g.z & 0xffff0000u), num[5]);
      num[6] = fmaf(eh, __uint_as_float(g.w << 16), num[6]);
      num[7] = fmaf(eh, __uint_as_float(g.w & 0xffff0000u), num[7]);
      rs += eh;
    }
  }

  // reduce over edge-slots (ii): xor 16, 32
#pragma unroll
  for (int mm = 16; mm <= 32; mm <<= 1) {
#pragma unroll
    for (int j = 0; j < 8; ++j) num[j] += __shfl_xor(num[j], mm);
    rs += __shfl_xor(rs, mm);
  }
  float inv = __frcp_rn(rs);
  float val[8];
#pragma unroll
  for (int j = 0; j < 8; ++j) val[j] = num[j] * inv;
  // reduce over heads (h bits): xor 4, 8
#pragma unroll
  for (int mm = 4; mm <= 8; mm <<= 1) {
#pragma unroll
    for (int j = 0; j < 8; ++j) val[j] += __shfl_xor(val[j], mm);
  }

  if (ii == 0) {
    int j0 = 2 * h;               // lane (h,cg) writes channels cg*8+2h, +1
    float a0 = val[j0] * 0.25f;
    float a1 = val[j0 + 1] * 0.25f;
    a0 = a0 > 0.f ? a0 : expm1f(a0);
    a1 = a1 > 0.f ? a1 : expm1f(a1);
    size_t o0 = ((size_t)(b * CC + cg * 8 + j0) * VV + v) * LL + l;
    outp[o0] = a0;
    outp[o0 + (size_t)VV * LL] = a1;
  }
}

// ---------------------------------------------------------------------------
extern "C" void kernel_launch(void* const* d_in, const int* in_sizes, int n_in,
                              void* d_out, int out_size, void* d_ws, size_t ws_size,
                              hipStream_t stream) {
  const float* x = (const float*)d_in[0];
  const float* W = (const float*)d_in[1];
  const float* a = (const float*)d_in[2];
  const int* ei = (const int*)d_in[3];
  const float* ev = (const float*)d_in[4];
  float* out = (float*)d_out;
  float* ws = (float*)d_ws;

  size_t o = 0;
  ushort* h_g = (ushort*)(ws + o);  o += (size_t)SS * VV * CC / 2;   // bf16, 12.3 MB
  float* s_src = ws + o;            o += SS * VV;
  float* s_dst = ws + o;            o += SS * VV;
  int* cnt = (int*)(ws + o);        o += 1024;
  uint2* csr = (uint2*)(ws + o);    o += (size_t)VV * RCAP * 2;      // {dst, lv}

  dim3 gA(VV / 2, BB);
  k_h<<<gA, 256, 0, stream>>>(x, W, a, h_g, s_src, s_dst, cnt);

  k_scatter<<<(EE + 255) / 256, 256, 0, stream>>>(ei, ev, cnt, csr);

  const int nblk = NBL * (VV / 4);  // 12000 blocks, 4 waves each
  k_agg<<<nblk, 256, 0, stream>>>(h_g, s_src, s_dst, cnt, csr, out);
}